// Round 5
// baseline (194.298 us; speedup 1.0000x reference)
//
#include <hip/hip_runtime.h>
#include <hip/hip_bf16.h>
#include <stdint.h>
#include <stddef.h>

typedef __bf16 bf16;
typedef float f32x4 __attribute__((ext_vector_type(4)));
typedef bf16 bf16x8 __attribute__((ext_vector_type(8)));
typedef bf16 bf16x4 __attribute__((ext_vector_type(4)));

#define MROWS 8192
#define NOUT 256
#define BM 32
#define BK 128
#define NTHREADS 512

#define LDS_A_BYTES (BM * BK * 2)  // 8 KiB bf16 A tile per slot

#define SCHED0 __builtin_amdgcn_sched_barrier(0)
#define SBAR __builtin_amdgcn_s_barrier()

// ---------------------------------------------------------------------------
// Bp fragment-permuted layout: for K-step ts, wave w, frag (bfi,ak), lane l,
// 16-byte lane chunk at byte offset (ts*64 + w*8 + bfi*4 + ak)*1024 + l*16,
// holding B[n][k0..k0+7], n = w*32+bfi*16+(l&15), k0 = ts*128+ak*32+(l>>4)*8.
// Producer map for (n,k): ts=k>>7, w=n>>5, bfi=(n>>4)&1, ak=(k>>5)&3,
//   l=((k>>3)&3)*16+(n&15), byte=(k&7)*2.
// ---------------------------------------------------------------------------

// ======================= deep-pipelined kernel (NT%4==0, NT>=4) =============
// Per step t: MFMA(afrC(t) x BC(t)) from regs; issue B(t+1), A(t+3);
// cvt+ds_write A(t+2) -> slot (t+2)&3; ds_read afrN(t+1) <- slot (t+1)&3;
// lgkm drain; barrier. Global loads stay in flight across the raw barrier.
template <bool SCALE, bool OUTT>
__global__ __launch_bounds__(NTHREADS, 1) void gemm_deep(
    const float* __restrict__ A, const bf16* __restrict__ Bp,
    const float* __restrict__ filt, void* __restrict__ outp,
    const int K, const int lda) {
  __shared__ char lds[4][LDS_A_BYTES];
  const int t = threadIdx.x;
  const int w = t >> 6;
  const int l = t & 63;
  const int m0 = blockIdx.x * BM;
  const int NT = K / BK;

  const int ar = t >> 4;
  const int acb = t & 15;
  const float* gA = A + (size_t)(m0 + ar) * (size_t)lda + acb * 8;
  const int a_lds_off = (ar * (BK * 2) + acb * 16) ^ ((ar & 7) << 4);

  int aoff[2][4];
#pragma unroll
  for (int af = 0; af < 2; ++af)
#pragma unroll
    for (int ak = 0; ak < 4; ++ak) {
      const int r = af * 16 + (l & 15);
      const int kb = ak * 64 + (l >> 4) * 16;
      aoff[af][ak] = (r * (BK * 2) + kb) ^ ((r & 7) << 4);
    }

  const char* pBw = (const char*)Bp + w * 8192 + l * 16;

  f32x4 acc[2][2] = {};

  // ---------------- prologue ----------------
  f32x4 A0a = __builtin_nontemporal_load((const f32x4*)gA);
  f32x4 A0b = __builtin_nontemporal_load((const f32x4*)gA + 1);
  f32x4 A1a = __builtin_nontemporal_load((const f32x4*)(gA + BK));
  f32x4 A1b = __builtin_nontemporal_load((const f32x4*)(gA + BK) + 1);
  bf16x8 B0[2][4], B1[2][4];
#pragma unroll
  for (int bfi = 0; bfi < 2; ++bfi)
#pragma unroll
    for (int ak = 0; ak < 4; ++ak)
      B0[bfi][ak] = *(const bf16x8*)(pBw + (bfi * 4 + ak) * 1024);
  f32x4 g0a = __builtin_nontemporal_load((const f32x4*)(gA + 2 * BK));
  f32x4 g0b = __builtin_nontemporal_load((const f32x4*)(gA + 2 * BK) + 1);
  f32x4 g1a, g1b;
  {
    bf16x8 pk;
#pragma unroll
    for (int j = 0; j < 4; ++j) { pk[j] = (bf16)A0a[j]; pk[j + 4] = (bf16)A0b[j]; }
    *(bf16x8*)(lds[0] + a_lds_off) = pk;
#pragma unroll
    for (int j = 0; j < 4; ++j) { pk[j] = (bf16)A1a[j]; pk[j + 4] = (bf16)A1b[j]; }
    *(bf16x8*)(lds[1] + a_lds_off) = pk;
  }
  asm volatile("s_waitcnt lgkmcnt(0)" ::: "memory");
  SBAR;
  SCHED0;
  bf16x8 f0[2][4], f1[2][4];
#pragma unroll
  for (int af = 0; af < 2; ++af)
#pragma unroll
    for (int ak = 0; ak < 4; ++ak)
      f0[af][ak] = *(const bf16x8*)(lds[0] + aoff[af][ak]);
  SCHED0;

#define BODY_D(TS, SW, SR, FC, FN, BCr, BNr, AC0, AC1, AN0, AN1)              \
  {                                                                           \
    const size_t kb1 = (size_t)((((TS) + 1) < NT ? ((TS) + 1) : 0)) << 16;    \
    _Pragma("unroll") for (int bfi = 0; bfi < 2; ++bfi)                       \
        _Pragma("unroll") for (int ak = 0; ak < 4; ++ak)                      \
            BNr[bfi][ak] =                                                    \
                *(const bf16x8*)(pBw + kb1 + (bfi * 4 + ak) * 1024);          \
    SCHED0;                                                                   \
    const int ka3 = ((((TS) + 3) < NT) ? ((TS) + 3) : 0) * BK;                \
    AN0 = __builtin_nontemporal_load((const f32x4*)(gA + ka3));               \
    AN1 = __builtin_nontemporal_load((const f32x4*)(gA + ka3) + 1);           \
    SCHED0;                                                                   \
    {                                                                         \
      bf16x8 pk;                                                              \
      _Pragma("unroll") for (int j = 0; j < 4; ++j) {                         \
        pk[j] = (bf16)AC0[j];                                                 \
        pk[j + 4] = (bf16)AC1[j];                                             \
      }                                                                       \
      *(bf16x8*)(lds[SW] + a_lds_off) = pk;                                   \
    }                                                                         \
    SCHED0;                                                                   \
    _Pragma("unroll") for (int af = 0; af < 2; ++af)                          \
        _Pragma("unroll") for (int ak = 0; ak < 4; ++ak)                      \
            FN[af][ak] = *(const bf16x8*)(lds[SR] + aoff[af][ak]);            \
    SCHED0;                                                                   \
    __builtin_amdgcn_s_setprio(1);                                            \
    _Pragma("unroll") for (int ak = 0; ak < 4; ++ak)                          \
        _Pragma("unroll") for (int af = 0; af < 2; ++af)                      \
            _Pragma("unroll") for (int bfi = 0; bfi < 2; ++bfi)               \
                acc[af][bfi] = __builtin_amdgcn_mfma_f32_16x16x32_bf16(       \
                    FC[af][ak], BCr[bfi][ak], acc[af][bfi], 0, 0, 0);         \
    __builtin_amdgcn_s_setprio(0);                                            \
    SCHED0;                                                                   \
    asm volatile("s_waitcnt lgkmcnt(0)" ::: "memory");                        \
    SBAR;                                                                     \
    SCHED0;                                                                   \
  }

  for (int ts = 0; ts < NT; ts += 4) {
    BODY_D(ts, 2, 1, f0, f1, B0, B1, g0a, g0b, g1a, g1b);
    BODY_D(ts + 1, 3, 2, f1, f0, B1, B0, g1a, g1b, g0a, g0b);
    BODY_D(ts + 2, 0, 3, f0, f1, B0, B1, g0a, g0b, g1a, g1b);
    BODY_D(ts + 3, 1, 0, f1, f0, B1, B0, g1a, g1b, g0a, g0b);
  }
#undef BODY_D

  // ---- epilogue (C/D: col = lane&15, row = (lane>>4)*4 + reg)
#pragma unroll
  for (int af = 0; af < 2; ++af)
#pragma unroll
    for (int bfi = 0; bfi < 2; ++bfi) {
      const int mb = m0 + af * 16 + (l >> 4) * 4;
      const int n = w * 32 + bfi * 16 + (l & 15);
      f32x4 v = acc[af][bfi];
      if (SCALE) {
#pragma unroll
        for (int j = 0; j < 4; ++j) v[j] *= filt[mb + j];
      }
      if (OUTT) {
        bf16x4 pv;
#pragma unroll
        for (int j = 0; j < 4; ++j) pv[j] = (bf16)v[j];
        const int tsq = mb >> 7, wq = n >> 5, bq = (n >> 4) & 1, aq = (mb >> 5) & 3;
        const int lq = ((mb >> 3) & 3) * 16 + (n & 15);
        char* dst = (char*)outp +
                    (size_t)(((tsq * 64 + wq * 8 + bq * 4 + aq) << 10) + lq * 16 +
                             (mb & 7) * 2);
        *(bf16x4*)dst = pv;
      } else {
        float* po = (float*)outp + (size_t)mb * NOUT + n;
#pragma unroll
        for (int j = 0; j < 4; ++j) po[(size_t)j * NOUT] = v[j];
      }
    }
}

// ======================= small-K kernel (round-4 schedule, NT>=2) ===========
template <bool SCALE, bool OUTT>
__global__ __launch_bounds__(NTHREADS, 1) void gemm_small(
    const float* __restrict__ A, const bf16* __restrict__ Bp,
    const float* __restrict__ filt, void* __restrict__ outp,
    const int K, const int lda) {
  __shared__ char lds[2][LDS_A_BYTES];
  const int t = threadIdx.x;
  const int w = t >> 6;
  const int l = t & 63;
  const int m0 = blockIdx.x * BM;
  const int NT = K / BK;

  const int ar = t >> 4;
  const int acb = t & 15;
  const float* gA = A + (size_t)(m0 + ar) * (size_t)lda + acb * 8;
  const int a_lds_off = (ar * (BK * 2) + acb * 16) ^ ((ar & 7) << 4);

  int aoff[2][4];
#pragma unroll
  for (int af = 0; af < 2; ++af)
#pragma unroll
    for (int ak = 0; ak < 4; ++ak) {
      const int r = af * 16 + (l & 15);
      const int kb = ak * 64 + (l >> 4) * 16;
      aoff[af][ak] = (r * (BK * 2) + kb) ^ ((r & 7) << 4);
    }

  const char* pBw = (const char*)Bp + w * 8192 + l * 16;

  f32x4 acc[2][2] = {};

  f32x4 aS0a = __builtin_nontemporal_load((const f32x4*)gA);
  f32x4 aS0b = __builtin_nontemporal_load((const f32x4*)gA + 1);
  f32x4 aS1a = __builtin_nontemporal_load((const f32x4*)(gA + BK));
  f32x4 aS1b = __builtin_nontemporal_load((const f32x4*)(gA + BK) + 1);
  bf16x8 Bc[2][4], Bn[2][4];
#pragma unroll
  for (int bfi = 0; bfi < 2; ++bfi)
#pragma unroll
    for (int ak = 0; ak < 4; ++ak)
      Bc[bfi][ak] = *(const bf16x8*)(pBw + (bfi * 4 + ak) * 1024);
  {
    bf16x8 pk;
#pragma unroll
    for (int j = 0; j < 4; ++j) { pk[j] = (bf16)aS0a[j]; pk[j + 4] = (bf16)aS0b[j]; }
    *(bf16x8*)(lds[0] + a_lds_off) = pk;
  }
  asm volatile("s_waitcnt lgkmcnt(0)" ::: "memory");
  SBAR;
  SCHED0;

#define BODY_S(TS, P, BCUR, BNXT, AW0, AW1, AL0, AL1)                         \
  {                                                                           \
    const char* bb = lds[P];                                                  \
    bf16x8 afr[2][4];                                                         \
    _Pragma("unroll") for (int af = 0; af < 2; ++af)                          \
        _Pragma("unroll") for (int ak = 0; ak < 4; ++ak)                      \
            afr[af][ak] = *(const bf16x8*)(bb + aoff[af][ak]);                \
    SCHED0;                                                                   \
    const size_t kb1 = (size_t)((((TS) + 1) < NT ? ((TS) + 1) : 0)) << 16;    \
    _Pragma("unroll") for (int bfi = 0; bfi < 2; ++bfi)                       \
        _Pragma("unroll") for (int ak = 0; ak < 4; ++ak)                      \
            BNXT[bfi][ak] =                                                   \
                *(const bf16x8*)(pBw + kb1 + (bfi * 4 + ak) * 1024);          \
    SCHED0;                                                                   \
    const int ka2 = (((TS) + 2) < NT ? ((TS) + 2) : 0) * BK;                  \
    AL0 = __builtin_nontemporal_load((const f32x4*)(gA + ka2));               \
    AL1 = __builtin_nontemporal_load((const f32x4*)(gA + ka2) + 1);           \
    SCHED0;                                                                   \
    asm volatile("s_waitcnt lgkmcnt(0)" ::: "memory");                        \
    SCHED0;                                                                   \
    __builtin_amdgcn_s_setprio(1);                                            \
    _Pragma("unroll") for (int ak = 0; ak < 4; ++ak)                          \
        _Pragma("unroll") for (int af = 0; af < 2; ++af)                      \
            _Pragma("unroll") for (int bfi = 0; bfi < 2; ++bfi)               \
                acc[af][bfi] = __builtin_amdgcn_mfma_f32_16x16x32_bf16(       \
                    afr[af][ak], BCUR[bfi][ak], acc[af][bfi], 0, 0, 0);       \
    __builtin_amdgcn_s_setprio(0);                                            \
    SCHED0;                                                                   \
    {                                                                         \
      bf16x8 pk;                                                              \
      _Pragma("unroll") for (int j = 0; j < 4; ++j) {                         \
        pk[j] = (bf16)AW0[j];                                                 \
        pk[j + 4] = (bf16)AW1[j];                                             \
      }                                                                       \
      *(bf16x8*)(lds[P ^ 1] + a_lds_off) = pk;                                \
    }                                                                         \
    asm volatile("s_waitcnt lgkmcnt(0)" ::: "memory");                        \
    SBAR;                                                                     \
    SCHED0;                                                                   \
  }

  for (int ts = 0; ts < NT; ts += 2) {
    BODY_S(ts, 0, Bc, Bn, aS1a, aS1b, aS0a, aS0b);
    BODY_S(ts + 1, 1, Bn, Bc, aS0a, aS0b, aS1a, aS1b);
  }
#undef BODY_S

#pragma unroll
  for (int af = 0; af < 2; ++af)
#pragma unroll
    for (int bfi = 0; bfi < 2; ++bfi) {
      const int mb = m0 + af * 16 + (l >> 4) * 4;
      const int n = w * 32 + bfi * 16 + (l & 15);
      f32x4 v = acc[af][bfi];
      if (SCALE) {
#pragma unroll
        for (int j = 0; j < 4; ++j) v[j] *= filt[mb + j];
      }
      if (OUTT) {
        bf16x4 pv;
#pragma unroll
        for (int j = 0; j < 4; ++j) pv[j] = (bf16)v[j];
        const int tsq = mb >> 7, wq = n >> 5, bq = (n >> 4) & 1, aq = (mb >> 5) & 3;
        const int lq = ((mb >> 3) & 3) * 16 + (n & 15);
        char* dst = (char*)outp +
                    (size_t)(((tsq * 64 + wq * 8 + bq * 4 + aq) << 10) + lq * 16 +
                             (mb & 7) * 2);
        *(bf16x4*)dst = pv;
      } else {
        float* po = (float*)outp + (size_t)mb * NOUT + n;
#pragma unroll
        for (int j = 0; j < 4; ++j) po[(size_t)j * NOUT] = v[j];
      }
    }
}

// W [256 k][256 n] fp32 -> Wp bf16 in Bp layout
__global__ void prep_wt(const float* __restrict__ W, bf16* __restrict__ Wp) {
  const int k = blockIdx.x;
  const int n = threadIdx.x;
  const int off = (((k >> 7) * 64 + (n >> 5) * 8 + ((n >> 4) & 1) * 4 +
                    ((k >> 5) & 3)) << 10) +
                  (((k >> 3) & 3) * 16 + (n & 15)) * 16 + (k & 7) * 2;
  *(bf16*)((char*)Wp + off) = (bf16)W[k * 256 + n];
}

extern "C" void kernel_launch(void* const* d_in, const int* in_sizes, int n_in,
                              void* d_out, int out_size, void* d_ws, size_t ws_size,
                              hipStream_t stream) {
  const float* features = (const float*)d_in[0];
  const float* wavelets = (const float*)d_in[1];
  const float* wavelets_inv = (const float*)d_in[2];
  const float* W = (const float*)d_in[3];
  const float* filt = (const float*)d_in[4];
  float* out = (float*)d_out;

  char* ws = (char*)d_ws;
  bf16* Wp = (bf16*)ws;                       // 128 KiB, Bp layout (K=256)
  bf16* Tp = (bf16*)(ws + 131072);            // 4 MiB, Bp layout (K=8192)
  bf16* Fp = (bf16*)(ws + 131072 + 4194304);  // 4 MiB, Bp layout (K=8192)

  prep_wt<<<256, 256, 0, stream>>>(W, Wp);
  gemm_small<false, true><<<256, NTHREADS, 0, stream>>>(features, Wp, nullptr, Tp, 256, 256);
  gemm_deep<true, true><<<256, NTHREADS, 0, stream>>>(wavelets_inv, Tp, filt, Fp, 8192, 8192);
  gemm_deep<false, false><<<256, NTHREADS, 0, stream>>>(wavelets, Fp, nullptr, out, 8192, 8192);
}